// Round 4
// baseline (321.527 us; speedup 1.0000x reference)
//
#include <hip/hip_runtime.h>
#include <hip/hip_bf16.h>

// Problem constants (fixed by the reference setup):
//   B=2000 graphs, LGPG=100 line-graph nodes/graph, NPG=20 nodes/graph,
//   ELPG=10 labeled edges/graph, D=300, HDIM=100 -> split at col 200.
#define D_      300
#define D4_     75        // D/4 float4s per row
#define H2_     200       // 2*HDIM: cols [0,200) <- incoming, [200,300) <- outgoing
#define NPGMAX  20
#define ROWMAX  128
#define BN_     2000
#define NNODES_ 40000
#define ELAB_   20000

__global__ __launch_bounds__(256) void main_kernel(
    const float* __restrict__ x, const int* __restrict__ lgidx,
    const int* __restrict__ ptr, const int* __restrict__ ogs,
    const int* __restrict__ els, const int* __restrict__ edge_in,
    float* __restrict__ out)
{
    // Output layout (element offsets into the flat FLOAT32 buffer):
    //   x_new   [40000,300] @ 0
    //   edge    [2,20000]   @ 12,000,000
    //   ptr_new [2001]      @ 12,040,000
    //   batch   [40000]     @ 12,042,001
    float* __restrict__ out_x     = out;
    float* __restrict__ out_edge  = out + (size_t)NNODES_ * D_;
    float* __restrict__ out_ptr   = out + (size_t)NNODES_ * D_ + 2 * ELAB_;
    float* __restrict__ out_batch = out + (size_t)NNODES_ * D_ + 2 * ELAB_ + (BN_ + 1);

    __shared__ float acc[NPGMAX * D_];     // 24 KB
    __shared__ int   cin[NPGMAX], cou[NPGMAX];
    __shared__ int   sidx[ROWMAX * 2];
    __shared__ int   s_r1[256], s_r2[256];

    const int g = blockIdx.x;
    const int t = threadIdx.x;

    // ---- Per-block exclusive prefix sums over ogs/els (no workspace). ----
    int p1 = 0, p2 = 0;
    for (int k = t; k < g; k += 256) { p1 += ogs[k]; p2 += els[k]; }
    s_r1[t] = p1; s_r2[t] = p2;
    __syncthreads();
    for (int s = 128; s > 0; s >>= 1) {
        if (t < s) { s_r1[t] += s_r1[t + s]; s_r2[t] += s_r2[t + s]; }
        __syncthreads();
    }
    const int nbase = s_r1[0];   // = sum ogs[0..g)
    const int eb    = s_r2[0];   // = sum els[0..g)
    __syncthreads();

    const int lg0 = ptr[g], lg1 = ptr[g + 1];
    int nrow = lg1 - lg0; if (nrow > ROWMAX) nrow = ROWMAX; if (nrow < 0) nrow = 0;
    const int npg_true = ogs[g];
    int npg = npg_true; if (npg > NPGMAX) npg = NPGMAX;

    for (int i = t; i < NPGMAX * D_; i += 256) acc[i] = 0.0f;
    if (t < NPGMAX) { cin[t] = 0; cou[t] = 0; }
    for (int i = t; i < nrow * 2; i += 256) sidx[i] = lgidx[(size_t)lg0 * 2 + i];
    __syncthreads();

    if (t < nrow) {
        atomicAdd(&cou[sidx[2 * t]], 1);       // outgoing: segment by lg_node_idx[:,0]
        atomicAdd(&cin[sidx[2 * t + 1]], 1);   // incoming: segment by lg_node_idx[:,1]
    }

    // Flat float4 sweep over this graph's x slice: nrow*75 float4s, contiguous.
    const int nf4 = nrow * D4_;
    const float4* xs = (const float4*)(x + (size_t)lg0 * D_);
    for (int f = t; f < nf4; f += 256) {
        float4 v = xs[f];
        int row = f / D4_;
        int c4  = f - row * D4_;
        int col = c4 * 4;                       // split at 200 is float4-aligned
        int seg = (col < H2_) ? sidx[2 * row + 1] : sidx[2 * row];
        float* a = &acc[seg * D_ + col];
        atomicAdd(a + 0, v.x);
        atomicAdd(a + 1, v.y);
        atomicAdd(a + 2, v.z);
        atomicAdd(a + 3, v.w);
    }
    __syncthreads();

    // Epilogue: mean + f32 store. acc index i = n*D_ + c, global out = nbase*D_ + i.
    const size_t obase = (size_t)nbase * D_;
    for (int i = t; i < npg * D_; i += 256) {
        int n = i / D_;
        int c = i - n * D_;
        int cnt = (c < H2_) ? cin[n] : cou[n];
        float val = (cnt > 0) ? acc[i] / (float)cnt : 0.0f;
        out_x[obase + i] = val;
    }

    // Small outputs, piggybacked per graph.
    if (t == 0) {
        out_ptr[g + 1] = (float)(nbase + npg_true);
        if (g == 0) out_ptr[0] = 0.0f;
    }
    for (int i = t; i < npg_true; i += 256)
        out_batch[nbase + i] = (float)g;

    const int nel = els[g];
    const int lgoff = lg0 - ptr[0];
    for (int j = t; j < nel; j += 256) {
        out_edge[eb + j]                 = (float)(edge_in[eb + j] - lgoff);
        out_edge[(size_t)ELAB_ + eb + j] = (float)(edge_in[(size_t)ELAB_ + eb + j] - lgoff);
    }
}

extern "C" void kernel_launch(void* const* d_in, const int* in_sizes, int n_in,
                              void* d_out, int out_size, void* d_ws, size_t ws_size,
                              hipStream_t stream)
{
    const float* x        = (const float*)d_in[0];
    const int*   lgidx    = (const int*)d_in[1];
    const int*   ptr      = (const int*)d_in[2];
    const int*   ogs      = (const int*)d_in[3];
    const int*   els      = (const int*)d_in[4];
    const int*   edge_in  = (const int*)d_in[5];

    main_kernel<<<BN_, 256, 0, stream>>>(x, lgidx, ptr, ogs, els, edge_in,
                                         (float*)d_out);
}